// Round 7
// baseline (357.943 us; speedup 1.0000x reference)
//
#include <hip/hip_runtime.h>
#include <stdint.h>

#define NCLASS 41
#define TLEN   1024
#define NBATCH 1024
// per-batch backpointer stride: (TLEN-1)*NCLASS = 41943, round to mult of 8
#define BP_STRIDE 41944
#define NTRANS (NCLASS * NCLASS)
#define NEGINF (-3.0e38f)
#define EPS    2.0e-3f

// Full-wave max + broadcast via DPP (row_shr 1/2/4/8, row_bcast 15/31).
// Lane 63 ends with the 64-lane max; readlane broadcasts it (uniform).
__device__ __forceinline__ float wave_max_bcast(float x) {
    int xi = __float_as_int(x);
    int t;
    t = __builtin_amdgcn_update_dpp(xi, xi, 0x111, 0xf, 0xf, false);  // row_shr:1
    x = fmaxf(x, __int_as_float(t)); xi = __float_as_int(x);
    t = __builtin_amdgcn_update_dpp(xi, xi, 0x112, 0xf, 0xf, false);  // row_shr:2
    x = fmaxf(x, __int_as_float(t)); xi = __float_as_int(x);
    t = __builtin_amdgcn_update_dpp(xi, xi, 0x114, 0xf, 0xf, false);  // row_shr:4
    x = fmaxf(x, __int_as_float(t)); xi = __float_as_int(x);
    t = __builtin_amdgcn_update_dpp(xi, xi, 0x118, 0xf, 0xf, false);  // row_shr:8
    x = fmaxf(x, __int_as_float(t)); xi = __float_as_int(x);
    t = __builtin_amdgcn_update_dpp(xi, xi, 0x142, 0xf, 0xf, false);  // row_bcast:15
    x = fmaxf(x, __int_as_float(t)); xi = __float_as_int(x);
    t = __builtin_amdgcn_update_dpp(xi, xi, 0x143, 0xf, 0xf, false);  // row_bcast:31
    x = fmaxf(x, __int_as_float(t));
    return __int_as_float(__builtin_amdgcn_readlane(__float_as_int(x), 63));
}

// ---------------------------------------------------------------------------
// Kernel A: Viterbi forward, pruned, with LAGGED threshold.
// thr for pruning score_t = M(score_{t-1}) + E_t + (Dmin - D - EPS), where
// E_t = max_j emit_t[j]. This is a valid lower bound of M_t - D - EPS
// (M_t >= M_{t-1} + E_t + Dmin), so the candidate set is a superset of the
// exact one -> bit-exact argmax (candidates processed in increasing i with
// strict >). The M/E DPP trees are OFF the critical chain: they issue inside
// the next step's LDS-wait window. Dual-candidate straight-line processing
// (both ds_reads overlap); while-loop only for |S|>=3 (rare).
// ---------------------------------------------------------------------------
__global__ __launch_bounds__(64, 1) void crf_forward(
    const float* __restrict__ x,        // [B, T, C]
    const float* __restrict__ start_t,  // [C]
    const float* __restrict__ end_t,    // [C]
    const float* __restrict__ trans,    // [C, C]
    uint8_t* __restrict__ bp,           // [B, BP_STRIDE]
    int* __restrict__ out)              // [B, T]
{
    __shared__ float tl[NTRANS + 32];   // trans rows; +pad so row reads never OOB

    const int b = blockIdx.x;
    const int j = threadIdx.x;
    const bool act = (j < NCLASS);
    const int jc = act ? j : (NCLASS - 1);  // clamped lane for always-valid loads

    // Stage trans into LDS and compute D = max - min (exact, from data)
    float mx = NEGINF, mn = 3.0e38f;
    for (int k = j; k < NTRANS; k += 64) {
        float v = trans[k];
        tl[k] = v;
        mx = fmaxf(mx, v);
        mn = fminf(mn, v);
    }
    __syncthreads();
    const float Dmax = wave_max_bcast(mx);
    const float Dmin = -wave_max_bcast(-mn);
    const float D = Dmax - Dmin;
    const float Cc = Dmin - D - EPS;    // lagged-threshold constant

    const float* xb = x + (size_t)b * TLEN * NCLASS;
    uint8_t* bpb = bp + (size_t)b * BP_STRIDE;

    float score = act ? (start_t[j] + xb[j]) : NEGINF;

    // Bootstrap threshold: exact (zero-lag) bound for step 1.
    float thr = wave_max_bcast(score) - D - EPS;

    // One Viterbi step. e = raw prefetched emission for this step.
    auto step = [&](float e, int t) {
        // ---- critical chain ----
        unsigned long long m = __ballot(score >= thr);
        unsigned long long mb = m & (m - 1);
        int i1 = __ffsll(m) - 1;
        int i2 = mb ? (__ffsll(mb) - 1) : i1;   // dup i1 when |S|==1
        unsigned long long m2 = mb & (mb - 1);
        float s1 = __int_as_float(
            __builtin_amdgcn_readlane(__float_as_int(score), i1));
        float s2 = __int_as_float(
            __builtin_amdgcn_readlane(__float_as_int(score), i2));
        float t1 = tl[i1 * NCLASS + jc];        // ds_read #1
        float t2 = tl[i2 * NCLASS + jc];        // ds_read #2 (overlaps #1)

        // ---- off-chain block: scheduled into the LDS-wait window ----
        float em = act ? e : NEGINF;            // masked emission
        float Mt = wave_max_bcast(score);       // M(score_{t-1}), lag-1 use
        float Et = wave_max_bcast(em);          // E_t
        float thrN = Mt + Et + Cc;              // next step's threshold

        // ---- chain resumes ----
        float v1 = s1 + t1;
        float v2 = s2 + t2;
        bool c = v2 > v1;                       // strict: first index wins ties
        float best = c ? v2 : v1;
        int bidx = c ? i2 : i1;
        while (m2) {                            // |S| >= 3: rare slow path
            int ic = __ffsll(m2) - 1;
            m2 &= m2 - 1;
            float sc = __int_as_float(
                __builtin_amdgcn_readlane(__float_as_int(score), ic));
            float vc = sc + tl[ic * NCLASS + jc];
            if (vc > best) { best = vc; bidx = ic; }
        }
        if (act) bpb[(size_t)(t - 1) * NCLASS + j] = (uint8_t)bidx;
        score = best + em;                      // inactive lanes stay ~NEGINF
        thr = thrN;
    };

    // Rolling 4-deep emission prefetch (rows t=1..4)
    float e0 = xb[1 * NCLASS + jc];
    float e1 = xb[2 * NCLASS + jc];
    float e2 = xb[3 * NCLASS + jc];
    float e3 = xb[4 * NCLASS + jc];

    int t0 = 1;
    for (; t0 + 3 <= TLEN - 4; t0 += 4) {  // t0 = 1..1017, steps 1..1020
        int r0 = t0 + 4, r1 = t0 + 5, r2 = t0 + 6, r3 = t0 + 7;
        r0 = r0 > TLEN - 1 ? TLEN - 1 : r0;
        r1 = r1 > TLEN - 1 ? TLEN - 1 : r1;
        r2 = r2 > TLEN - 1 ? TLEN - 1 : r2;
        r3 = r3 > TLEN - 1 ? TLEN - 1 : r3;
        step(e0, t0 + 0); e0 = xb[(size_t)r0 * NCLASS + jc];
        step(e1, t0 + 1); e1 = xb[(size_t)r1 * NCLASS + jc];
        step(e2, t0 + 2); e2 = xb[(size_t)r2 * NCLASS + jc];
        step(e3, t0 + 3); e3 = xb[(size_t)r3 * NCLASS + jc];
    }
    // Tail steps 1021..1023 (prefetched in the last group; e3 unused)
    step(e0, TLEN - 3);
    step(e1, TLEN - 2);
    step(e2, TLEN - 1);

    // Final: add end transitions, argmax over lanes (first-index on tie)
    float fs = act ? (score + end_t[j]) : NEGINF;
    int idx = j;
#pragma unroll
    for (int off = 32; off >= 1; off >>= 1) {
        float ov = __shfl_xor(fs, off);
        int oi = __shfl_xor(idx, off);
        if (ov > fs || (ov == fs && oi < idx)) { fs = ov; idx = oi; }
    }
    if (j == 0) out[(size_t)b * TLEN + (TLEN - 1)] = idx;
}

// ---------------------------------------------------------------------------
// Kernel B: backtracking (unchanged; measured cheap).
// ---------------------------------------------------------------------------
__global__ __launch_bounds__(1024) void crf_backtrack(
    const uint8_t* __restrict__ bp,
    int* __restrict__ out)
{
    __shared__ uint8_t bpl[BP_STRIDE];     // 41944 B
    __shared__ int maps[16][NCLASS];       // chunk boundary maps
    __shared__ int entry[16];              // true tag at each chunk end

    const int b = blockIdx.x;
    const int tid = threadIdx.x;
    const int w = tid >> 6;
    const int lane = tid & 63;

    {
        const uint32_t* src = (const uint32_t*)(bp + (size_t)b * BP_STRIDE);
        uint32_t* dst = (uint32_t*)bpl;
        for (int i = tid; i < BP_STRIDE / 4; i += 1024) dst[i] = src[i];
    }
    __syncthreads();

    const int cs = w * 64;
    const int ce = min(cs + 64, TLEN - 1);  // last chunk: 63 columns
    const int L = ce - cs;

    // Phase 1: hypothesis walk for all 41 entering tags (lane = hypothesis)
    {
        int xx = (lane < NCLASS) ? lane : 0;
        for (int t = ce; t > cs; --t)
            xx = bpl[(t - 1) * NCLASS + xx];
        if (lane < NCLASS) maps[w][lane] = xx;
    }
    __syncthreads();

    // Stitch chunk boundaries serially on one thread
    if (tid == 0) {
        int cur = out[(size_t)b * TLEN + (TLEN - 1)];  // tag @ T-1 from kernel A
        for (int ww = 15; ww >= 0; --ww) {
            entry[ww] = cur;
            cur = maps[ww][cur];
        }
    }
    __syncthreads();

    // Phase 2: replay with true entering tag; lane l captures step l's tag
    {
        int xx = entry[w];
        int cap = 0;
        for (int k = 0; k < L; ++k) {
            xx = bpl[(ce - 1 - k) * NCLASS + xx];
            if (k == lane) cap = xx;
        }
        if (lane < L) out[(size_t)b * TLEN + (ce - 1 - lane)] = cap;
    }
}

// ---------------------------------------------------------------------------
extern "C" void kernel_launch(void* const* d_in, const int* in_sizes, int n_in,
                              void* d_out, int out_size, void* d_ws, size_t ws_size,
                              hipStream_t stream) {
    const float* x       = (const float*)d_in[0];
    const float* start_t = (const float*)d_in[1];
    const float* end_t   = (const float*)d_in[2];
    const float* trans   = (const float*)d_in[3];
    int* out = (int*)d_out;
    uint8_t* bp = (uint8_t*)d_ws;  // needs NBATCH * BP_STRIDE = ~42.9 MB

    crf_forward<<<NBATCH, 64, 0, stream>>>(x, start_t, end_t, trans, bp, out);
    crf_backtrack<<<NBATCH, 1024, 0, stream>>>(bp, out);
}